// Round 1
// baseline (3467.100 us; speedup 1.0000x reference)
//
#include <hip/hip_runtime.h>
#include <hip/hip_bf16.h>

// Shapes: B=2, H=W=64, HW=4096, DIM=32, HID=128
#define HWSZ 4096

__device__ __forceinline__ float gelu_f(float v) {
    return 0.5f * v * (1.0f + erff(v * 0.7071067811865475f));
}

// ---------------- K1: x(B,HW,32) @ w1(32,128) + b1, gelu, store channels-first (B,128,HW)
__global__ __launch_bounds__(256) void k1_fc1(const float* __restrict__ x,
                                              const float* __restrict__ w1,
                                              const float* __restrict__ b1,
                                              float* __restrict__ xi) {
    int idx = blockIdx.x * 256 + threadIdx.x;  // (b,c,p)
    int p = idx & 4095;
    int c = (idx >> 12) & 127;
    int b = idx >> 19;
    const float* xr = x + (size_t)(b * HWSZ + p) * 32;
    float acc = b1[c];
#pragma unroll
    for (int k = 0; k < 32; ++k) acc = fmaf(xr[k], w1[k * 128 + c], acc);
    xi[idx] = gelu_f(acc);
}

// ---------------- K2: depthwise 3x3 (pad 1), + bias, no activation
__global__ __launch_bounds__(256) void k2_dw(const float* __restrict__ xi,
                                             const float* __restrict__ dww,
                                             const float* __restrict__ dwb,
                                             float* __restrict__ dwo) {
    int idx = blockIdx.x * 256 + threadIdx.x;  // (b,c,p)
    int p = idx & 4095;
    int c = (idx >> 12) & 127;
    int h = p >> 6, w = p & 63;
    const float* plane = xi + (size_t)(idx >> 12) * HWSZ;
    float acc = dwb[c];
    for (int i = 0; i < 3; ++i) {
        int y = h + i - 1;
        if (y < 0 || y > 63) continue;
        for (int j = 0; j < 3; ++j) {
            int xx = w + j - 1;
            if (xx < 0 || xx > 63) continue;
            acc = fmaf(plane[y * 64 + xx], dww[c * 9 + i * 3 + j], acc);
        }
    }
    dwo[idx] = acc;
}

// ---------------- K3: pointwise 128->256, + bias, gelu
__global__ __launch_bounds__(256) void k3_pw(const float* __restrict__ dwo,
                                             const float* __restrict__ pww,
                                             const float* __restrict__ pwb,
                                             float* __restrict__ y) {
    int idx = blockIdx.x * 256 + threadIdx.x;  // (b,o(256),p)
    int p = idx & 4095;
    int o = (idx >> 12) & 255;
    int b = idx >> 20;
    const float* din = dwo + (size_t)b * 128 * HWSZ;
    const float* wr = pww + o * 128;
    float acc = pwb[o];
    for (int c = 0; c < 128; ++c) acc = fmaf(din[c * HWSZ + p], wr[c], acc);
    y[idx] = gelu_f(acc);
}

// ---------------- weight re-layout (O=128,C=128,T) -> (T,C,O)
__global__ __launch_bounds__(256) void wtk(const float* __restrict__ w,
                                           float* __restrict__ wt, int T) {
    int idx = blockIdx.x * 256 + threadIdx.x;  // (t,c,o)
    int o = idx & 127;
    int c = (idx >> 7) & 127;
    int t = idx >> 14;
    wt[idx] = w[(size_t)(o * 128 + c) * T + t];
}

// ---------------- channels-first -> channels-last (B,HW,128)
__global__ __launch_bounds__(256) void tcl(const float* __restrict__ in,
                                           float* __restrict__ out, int bstride) {
    int idx = blockIdx.x * 256 + threadIdx.x;  // (b,p,c)
    int c = idx & 127;
    int p = (idx >> 7) & 4095;
    int b = idx >> 19;
    out[idx] = in[(size_t)b * bstride + (size_t)c * HWSZ + p];
}

// ---------------- K4: offset conv, kxk pad, 128 -> OC channels (channels-first in/out)
__global__ __launch_bounds__(256) void k4_off(const float* __restrict__ ain, int bstride,
                                              const float* __restrict__ offw,
                                              const float* __restrict__ offb,
                                              float* __restrict__ off,
                                              int OC, int k, int pad) {
    int idx = blockIdx.x * 256 + threadIdx.x;  // (b,oc,p)
    int p = idx & 4095;
    int rest = idx >> 12;
    int oc = rest % OC;
    int b = rest / OC;
    int h = p >> 6, w = p & 63;
    const float* ab = ain + (size_t)b * bstride;
    const float* wr = offw + (size_t)oc * 128 * k * k;
    float acc = offb[oc];
    for (int c = 0; c < 128; ++c) {
        const float* plane = ab + (size_t)c * HWSZ;
        const float* wc = wr + c * k * k;
        for (int ky = 0; ky < k; ++ky) {
            int yy = h + ky - pad;
            if (yy < 0 || yy > 63) continue;
            for (int kx = 0; kx < k; ++kx) {
                int xx = w + kx - pad;
                if (xx < 0 || xx > 63) continue;
                acc = fmaf(plane[yy * 64 + xx], wc[ky * k + kx], acc);
            }
        }
    }
    off[idx] = acc;  // (b,oc,p)
}

// ---------------- K5: deformable sample + (128x128 per-tap) matvec + bias + gelu
// ain_cl: (B,HW,128) channels-last; off: (B,2T,HW); wt: (T,C,O); out: (B,128,HW)
__global__ __launch_bounds__(256) void k5_deform(const float* __restrict__ ain_cl,
                                                 const float* __restrict__ off,
                                                 const float* __restrict__ wt,
                                                 const float* __restrict__ bias,
                                                 float* __restrict__ out_cf,
                                                 int T, int k, int pad) {
    __shared__ float v[16][128];
    __shared__ float swgt[4][16];
    __shared__ int sidx[4][16];
    int tid = threadIdx.x;
    int blk = blockIdx.x;       // B*256 blocks
    int b = blk >> 8;
    int p0 = (blk & 255) << 4;  // 16 pixels per block
    int o = tid & 127;
    int pg = tid >> 7;  // 0/1 -> pixels pg*8..pg*8+7
    float acc[8];
#pragma unroll
    for (int r = 0; r < 8; ++r) acc[r] = 0.f;
    const float* ain_b = ain_cl + (size_t)b * HWSZ * 128;
    const float* off_b = off + (size_t)b * 2 * T * HWSZ;

    for (int t = 0; t < T; ++t) {
        int ky = t / k, kx = t - ky * k;
        __syncthreads();  // previous iter done with v/swgt/sidx
        if (tid < 16) {
            int p = p0 + tid;
            int h = p >> 6, w = p & 63;
            float dy = off_b[(size_t)(2 * t) * HWSZ + p];
            float dx = off_b[(size_t)(2 * t + 1) * HWSZ + p];
            float py = (float)(h + ky - pad) + dy;
            float px = (float)(w + kx - pad) + dx;
            float y0f = floorf(py), x0f = floorf(px);
            float wy = py - y0f, wx = px - x0f;
            int y0 = (int)y0f, x0 = (int)x0f;
            int y1 = y0 + 1, x1 = x0 + 1;
            float w00 = (1.f - wy) * (1.f - wx), w01 = (1.f - wy) * wx;
            float w10 = wy * (1.f - wx), w11 = wy * wx;
            int cy0 = min(max(y0, 0), 63), cy1 = min(max(y1, 0), 63);
            int cx0 = min(max(x0, 0), 63), cx1 = min(max(x1, 0), 63);
            bool vy0 = (y0 >= 0) && (y0 < 64), vy1 = (y1 >= 0) && (y1 < 64);
            bool vx0 = (x0 >= 0) && (x0 < 64), vx1 = (x1 >= 0) && (x1 < 64);
            swgt[0][tid] = (vy0 && vx0) ? w00 : 0.f; sidx[0][tid] = cy0 * 64 + cx0;
            swgt[1][tid] = (vy0 && vx1) ? w01 : 0.f; sidx[1][tid] = cy0 * 64 + cx1;
            swgt[2][tid] = (vy1 && vx0) ? w10 : 0.f; sidx[2][tid] = cy1 * 64 + cx0;
            swgt[3][tid] = (vy1 && vx1) ? w11 : 0.f; sidx[3][tid] = cy1 * 64 + cx1;
        }
        __syncthreads();
        // sample 16 pixels x 128 channels over 256 threads (8 each)
#pragma unroll
        for (int j = 0; j < 8; ++j) {
            int s = j * 256 + tid;
            int i = s >> 7, c = s & 127;
            float val = swgt[0][i] * ain_b[(size_t)sidx[0][i] * 128 + c]
                      + swgt[1][i] * ain_b[(size_t)sidx[1][i] * 128 + c]
                      + swgt[2][i] * ain_b[(size_t)sidx[2][i] * 128 + c]
                      + swgt[3][i] * ain_b[(size_t)sidx[3][i] * 128 + c];
            v[i][c] = val;
        }
        __syncthreads();
        const float* wt_t = wt + (size_t)t * 128 * 128;
        for (int c = 0; c < 128; ++c) {
            float wv = wt_t[c * 128 + o];
#pragma unroll
            for (int r = 0; r < 8; ++r) acc[r] = fmaf(v[pg * 8 + r][c], wv, acc[r]);
        }
    }
    float bo = bias[o];
    float* out_b = out_cf + ((size_t)b * 128 + o) * HWSZ;
#pragma unroll
    for (int r = 0; r < 8; ++r) out_b[p0 + pg * 8 + r] = gelu_f(acc[r] + bo);
}

// ---------------- KZ: z = gelu(a) * g  (channels-first)
__global__ __launch_bounds__(256) void kz(const float* __restrict__ a,
                                          const float* __restrict__ y,
                                          float* __restrict__ z) {
    int idx = blockIdx.x * 256 + threadIdx.x;  // (b,c,p)
    int p = idx & 4095;
    int c = (idx >> 12) & 127;
    int b = idx >> 19;
    float g = y[((size_t)(b * 256 + 128 + c)) * HWSZ + p];
    z[idx] = gelu_f(a[idx]) * g;
}

// ---------------- K6: out(B,HW,32) = z(B,128,HW)^T @ w2(128,32) + b2
__global__ __launch_bounds__(256) void k6_fc2(const float* __restrict__ z,
                                              const float* __restrict__ w2,
                                              const float* __restrict__ b2,
                                              float* __restrict__ out) {
    int idx = blockIdx.x * 256 + threadIdx.x;  // (b,p,d)
    int d = idx & 31;
    int p = (idx >> 5) & 4095;
    int b = idx >> 17;
    const float* zb = z + (size_t)b * 128 * HWSZ;
    float acc = b2[d];
    for (int c = 0; c < 128; ++c) acc = fmaf(zb[c * HWSZ + p], w2[c * 32 + d], acc);
    out[idx] = acc;
}

extern "C" void kernel_launch(void* const* d_in, const int* in_sizes, int n_in,
                              void* d_out, int out_size, void* d_ws, size_t ws_size,
                              hipStream_t stream) {
    const float* x   = (const float*)d_in[0];
    const float* w1  = (const float*)d_in[1];
    const float* b1  = (const float*)d_in[2];
    const float* dww = (const float*)d_in[3];
    const float* dwb = (const float*)d_in[4];
    const float* pww = (const float*)d_in[5];
    const float* pwb = (const float*)d_in[6];
    const float* o3w = (const float*)d_in[7];
    const float* o3b = (const float*)d_in[8];
    const float* d3w = (const float*)d_in[9];
    const float* d3b = (const float*)d_in[10];
    const float* o4w = (const float*)d_in[11];
    const float* o4b = (const float*)d_in[12];
    const float* d4w = (const float*)d_in[13];
    const float* d4b = (const float*)d_in[14];
    const float* o5w = (const float*)d_in[15];
    const float* o5b = (const float*)d_in[16];
    const float* d5w = (const float*)d_in[17];
    const float* d5b = (const float*)d_in[18];
    const float* w2  = (const float*)d_in[19];
    const float* b2  = (const float*)d_in[20];

    float* ws = (float*)d_ws;
    float* xi   = ws;                 // 1,048,576
    float* dwo  = ws + 1048576;       // 1,048,576
    float* y    = ws + 2097152;       // 2,097,152
    float* acl  = ws + 4194304;       // 1,048,576
    float* offb = ws + 5242880;       //   802,816 (max 2*98*4096)
    float* a2   = ws + 6045696;       // 1,048,576
    float* a3   = ws + 7094272;       // 1,048,576
    float* wt3  = ws + 8142848;       //   802,816
    float* wt4  = ws + 8945664;       //   147,456
    float* wt5  = ws + 9093120;       //   409,600

    k1_fc1<<<4096, 256, 0, stream>>>(x, w1, b1, xi);
    k2_dw<<<4096, 256, 0, stream>>>(xi, dww, dwb, dwo);
    k3_pw<<<8192, 256, 0, stream>>>(dwo, pww, pwb, y);

    wtk<<<(16384 * 49) / 256, 256, 0, stream>>>(d3w, wt3, 49);
    wtk<<<(16384 * 9) / 256, 256, 0, stream>>>(d4w, wt4, 9);
    wtk<<<(16384 * 25) / 256, 256, 0, stream>>>(d5w, wt5, 25);

    // d3: input a = first 128 channels of y
    tcl<<<4096, 256, 0, stream>>>(y, acl, 256 * HWSZ);
    k4_off<<<(2 * 98 * HWSZ) / 256, 256, 0, stream>>>(y, 256 * HWSZ, o3w, o3b, offb, 98, 7, 3);
    k5_deform<<<512, 256, 0, stream>>>(acl, offb, wt3, d3b, a2, 49, 7, 3);

    // d4
    tcl<<<4096, 256, 0, stream>>>(a2, acl, 128 * HWSZ);
    k4_off<<<(2 * 18 * HWSZ) / 256, 256, 0, stream>>>(a2, 128 * HWSZ, o4w, o4b, offb, 18, 3, 1);
    k5_deform<<<512, 256, 0, stream>>>(acl, offb, wt4, d4b, a3, 9, 3, 1);

    // d5
    tcl<<<4096, 256, 0, stream>>>(a3, acl, 128 * HWSZ);
    k4_off<<<(2 * 50 * HWSZ) / 256, 256, 0, stream>>>(a3, 128 * HWSZ, o5w, o5b, offb, 50, 5, 2);
    k5_deform<<<512, 256, 0, stream>>>(acl, offb, wt5, d5b, a2, 25, 5, 2);

    // z = gelu(a) * g ; out = z @ w2 + b2
    kz<<<4096, 256, 0, stream>>>(a2, y, a3);
    k6_fc2<<<1024, 256, 0, stream>>>(a3, w2, b2, (float*)d_out);
}

// Round 2
// 879.483 us; speedup vs baseline: 3.9422x; 3.9422x over previous
//
#include <hip/hip_runtime.h>
#include <hip/hip_bf16.h>

// Shapes: B=2, H=W=64, HW=4096, DIM=32, HID=128
#define HWSZ 4096

typedef _Float16 half8 __attribute__((ext_vector_type(8)));
typedef float f32x4 __attribute__((ext_vector_type(4)));

__device__ __forceinline__ float gelu_f(float v) {
    return 0.5f * v * (1.0f + erff(v * 0.7071067811865475f));
}

// ---------------- K1: x(B,HW,32) @ w1(32,128) + b1, gelu, store channels-first (B,128,HW)
__global__ __launch_bounds__(256) void k1_fc1(const float* __restrict__ x,
                                              const float* __restrict__ w1,
                                              const float* __restrict__ b1,
                                              float* __restrict__ xi) {
    int idx = blockIdx.x * 256 + threadIdx.x;  // (b,c,p)
    int p = idx & 4095;
    int c = (idx >> 12) & 127;
    int b = idx >> 19;
    const float* xr = x + (size_t)(b * HWSZ + p) * 32;
    float acc = b1[c];
#pragma unroll
    for (int k = 0; k < 32; ++k) acc = fmaf(xr[k], w1[k * 128 + c], acc);
    xi[idx] = gelu_f(acc);
}

// ---------------- K2: depthwise 3x3 (pad 1), + bias
__global__ __launch_bounds__(256) void k2_dw(const float* __restrict__ xi,
                                             const float* __restrict__ dww,
                                             const float* __restrict__ dwb,
                                             float* __restrict__ dwo) {
    int idx = blockIdx.x * 256 + threadIdx.x;  // (b,c,p)
    int p = idx & 4095;
    int c = (idx >> 12) & 127;
    int h = p >> 6, w = p & 63;
    const float* plane = xi + (size_t)(idx >> 12) * HWSZ;
    float acc = dwb[c];
    for (int i = 0; i < 3; ++i) {
        int y = h + i - 1;
        if (y < 0 || y > 63) continue;
        for (int j = 0; j < 3; ++j) {
            int xx = w + j - 1;
            if (xx < 0 || xx > 63) continue;
            acc = fmaf(plane[y * 64 + xx], dww[c * 9 + i * 3 + j], acc);
        }
    }
    dwo[idx] = acc;
}

// ---------------- K3: pointwise 128->256, + bias, gelu
__global__ __launch_bounds__(256) void k3_pw(const float* __restrict__ dwo,
                                             const float* __restrict__ pww,
                                             const float* __restrict__ pwb,
                                             float* __restrict__ y) {
    int idx = blockIdx.x * 256 + threadIdx.x;  // (b,o(256),p)
    int p = idx & 4095;
    int o = (idx >> 12) & 255;
    int b = idx >> 20;
    const float* din = dwo + (size_t)b * 128 * HWSZ;
    const float* wr = pww + o * 128;
    float acc = pwb[o];
    for (int c = 0; c < 128; ++c) acc = fmaf(din[c * HWSZ + p], wr[c], acc);
    y[idx] = gelu_f(acc);
}

// ---------------- zero a channels-last padded buffer (as uints)
__global__ __launch_bounds__(256) void zcl(unsigned int* __restrict__ p) {
    p[blockIdx.x * 256 + threadIdx.x] = 0u;
}

// ---------------- P1: y[:, :128] f32 channels-first -> clA (B,70,72,128) f16, zero halo
__global__ __launch_bounds__(256) void p1_cl(const float* __restrict__ y,
                                             _Float16* __restrict__ cl) {
    int idx = blockIdx.x * 256 + threadIdx.x;  // (b,hh,ww,c)
    int c = idx & 127;
    int t = idx >> 7;
    int ww = t % 72;
    int t2 = t / 72;
    int hh = t2 % 70;
    int b = t2 / 70;
    float v = 0.f;
    if (hh >= 3 && hh < 67 && ww >= 3 && ww < 67)
        v = y[((size_t)(b * 256 + c)) * HWSZ + (hh - 3) * 64 + (ww - 3)];
    cl[idx] = (_Float16)v;
}

// ---------------- weight transform: (O,128,T) f32 -> (T,Op,128) f16, scaled, zero-pad rows
__global__ __launch_bounds__(256) void wtr(const float* __restrict__ w,
                                           _Float16* __restrict__ o,
                                           int T, int Op, int O, float scale) {
    int idx = blockIdx.x * 256 + threadIdx.x;  // (t, op, c)
    int c = idx & 127;
    int op = (idx >> 7) % Op;
    int t = idx / (128 * Op);
    float v = (op < O) ? w[((size_t)(op * 128 + c)) * T + t] * scale : 0.f;
    o[idx] = (_Float16)v;
}

// ---------------- K4G: offset conv as implicit-im2col MFMA GEMM
// cl: (B,70,72,128) f16 padded CL. wA: (T, OCp=MT*16, 128) f16 (scaled x256).
// out offb: (B, OCp, 4096) f32.
template <int MT, int KK, int PAD, int T>
__global__ __launch_bounds__(256) void k4G(const _Float16* __restrict__ cl,
                                           const _Float16* __restrict__ wA,
                                           const float* __restrict__ obias,
                                           float* __restrict__ offb, int OC) {
    int tid = threadIdx.x;
    int wv = tid >> 6;
    int l = tid & 63;
    int col = l & 15, kg = l >> 4;
    int blk = blockIdx.x;
    int b = blk >> 6, h = blk & 63;
    int px0 = wv * 16;
    const int OCp = MT * 16;
    f32x4 acc[MT];
#pragma unroll
    for (int m = 0; m < MT; ++m) acc[m] = (f32x4){0.f, 0.f, 0.f, 0.f};
    const _Float16* clb = cl + (size_t)b * 70 * 72 * 128;
    for (int t = 0; t < T; ++t) {
        int ky = t / KK, kx = t % KK;
        int hh = h + ky + (3 - PAD);
        int ww = px0 + col + kx + (3 - PAD);
        const _Float16* bp = clb + ((size_t)hh * 72 + ww) * 128 + kg * 8;
        const _Float16* ap = wA + ((size_t)t * OCp + col) * 128 + kg * 8;
#pragma unroll
        for (int cc = 0; cc < 4; ++cc) {
            half8 bf = *(const half8*)(bp + cc * 32);
#pragma unroll
            for (int m = 0; m < MT; ++m) {
                half8 af = *(const half8*)(ap + (size_t)m * 16 * 128 + cc * 32);
                acc[m] = __builtin_amdgcn_mfma_f32_16x16x32_f16(af, bf, acc[m], 0, 0, 0);
            }
        }
    }
    int px = h * 64 + px0 + col;
#pragma unroll
    for (int m = 0; m < MT; ++m) {
#pragma unroll
        for (int r = 0; r < 4; ++r) {
            int oc = m * 16 + kg * 4 + r;
            float v = acc[m][r] * (1.0f / 256.0f) + (oc < OC ? obias[oc] : 0.f);
            offb[((size_t)(b * OCp + oc)) * HWSZ + px] = v;
        }
    }
}

// ---------------- K5G: deformable conv as sampled-B MFMA GEMM
// cl: input CL f16 padded. offb: (B, OFFP, 4096) f32. wM: (T,128,128) f16 (x16).
// MODE 0: write CL f16 padded (outH) interior. MODE 1: write CF f32 (outF).
template <int KK, int PAD, int T, int MODE>
__global__ __launch_bounds__(256) void k5G(const _Float16* __restrict__ cl,
                                           const float* __restrict__ offb, int OFFP,
                                           const _Float16* __restrict__ wM,
                                           const float* __restrict__ bias,
                                           float* __restrict__ outF,
                                           _Float16* __restrict__ outH) {
    int tid = threadIdx.x;
    int wv = tid >> 6;
    int l = tid & 63;
    int col = l & 15, kg = l >> 4;
    int blk = blockIdx.x;
    int b = blk >> 6, h = blk & 63;
    int px0 = wv * 16;
    int w = px0 + col;
    int px = h * 64 + w;
    f32x4 acc[8];
#pragma unroll
    for (int m = 0; m < 8; ++m) acc[m] = (f32x4){0.f, 0.f, 0.f, 0.f};
    const _Float16* clb = cl + (size_t)b * 70 * 72 * 128;
    const float* ob = offb + (size_t)b * OFFP * HWSZ;
    for (int t = 0; t < T; ++t) {
        int ky = t / KK, kx = t % KK;
        float dy = ob[(size_t)(2 * t) * HWSZ + px];
        float dx = ob[(size_t)(2 * t + 1) * HWSZ + px];
        float py = (float)(h + ky - PAD) + dy;
        float pxs = (float)(w + kx - PAD) + dx;
        float y0f = floorf(py), x0f = floorf(pxs);
        float wy = py - y0f, wx = pxs - x0f;
        int y0 = (int)y0f, x0 = (int)x0f;
        int y1 = y0 + 1, x1 = x0 + 1;
        bool vy0 = (y0 >= 0) && (y0 < 64), vy1 = (y1 >= 0) && (y1 < 64);
        bool vx0 = (x0 >= 0) && (x0 < 64), vx1 = (x1 >= 0) && (x1 < 64);
        float w00 = (vy0 && vx0) ? (1.f - wy) * (1.f - wx) : 0.f;
        float w01 = (vy0 && vx1) ? (1.f - wy) * wx : 0.f;
        float w10 = (vy1 && vx0) ? wy * (1.f - wx) : 0.f;
        float w11 = (vy1 && vx1) ? wy * wx : 0.f;
        int cy0 = min(max(y0, 0), 63) + 3, cy1 = min(max(y1, 0), 63) + 3;
        int cx0 = min(max(x0, 0), 63) + 3, cx1 = min(max(x1, 0), 63) + 3;
        const _Float16* p00 = clb + ((size_t)cy0 * 72 + cx0) * 128 + kg * 8;
        const _Float16* p01 = clb + ((size_t)cy0 * 72 + cx1) * 128 + kg * 8;
        const _Float16* p10 = clb + ((size_t)cy1 * 72 + cx0) * 128 + kg * 8;
        const _Float16* p11 = clb + ((size_t)cy1 * 72 + cx1) * 128 + kg * 8;
        const _Float16* ap = wM + ((size_t)t * 128 + col) * 128 + kg * 8;
#pragma unroll
        for (int cc = 0; cc < 4; ++cc) {
            half8 a00 = *(const half8*)(p00 + cc * 32);
            half8 a01 = *(const half8*)(p01 + cc * 32);
            half8 a10 = *(const half8*)(p10 + cc * 32);
            half8 a11 = *(const half8*)(p11 + cc * 32);
            half8 bf;
#pragma unroll
            for (int j = 0; j < 8; ++j) {
                float v = w00 * (float)a00[j] + w01 * (float)a01[j] +
                          w10 * (float)a10[j] + w11 * (float)a11[j];
                bf[j] = (_Float16)v;
            }
#pragma unroll
            for (int m = 0; m < 8; ++m) {
                half8 af = *(const half8*)(ap + (size_t)m * 16 * 128 + cc * 32);
                acc[m] = __builtin_amdgcn_mfma_f32_16x16x32_f16(af, bf, acc[m], 0, 0, 0);
            }
        }
    }
#pragma unroll
    for (int m = 0; m < 8; ++m) {
        if (MODE == 1) {
#pragma unroll
            for (int r = 0; r < 4; ++r) {
                int oc = m * 16 + kg * 4 + r;
                float v = gelu_f(acc[m][r] * (1.0f / 16.0f) + bias[oc]);
                outF[((size_t)(b * 128 + oc)) * HWSZ + px] = v;
            }
        } else {
            _Float16 t4[4];
#pragma unroll
            for (int r = 0; r < 4; ++r) {
                int oc = m * 16 + kg * 4 + r;
                t4[r] = (_Float16)gelu_f(acc[m][r] * (1.0f / 16.0f) + bias[oc]);
            }
            _Float16* dst = outH + (size_t)b * 70 * 72 * 128 +
                            ((size_t)(h + 3) * 72 + (3 + w)) * 128 + m * 16 + kg * 4;
            *(uint2*)dst = *(uint2*)t4;
        }
    }
}

// ---------------- KZ: z = gelu(a) * g  (channels-first)
__global__ __launch_bounds__(256) void kz(const float* __restrict__ a,
                                          const float* __restrict__ y,
                                          float* __restrict__ z) {
    int idx = blockIdx.x * 256 + threadIdx.x;  // (b,c,p)
    int p = idx & 4095;
    int c = (idx >> 12) & 127;
    int b = idx >> 19;
    float g = y[((size_t)(b * 256 + 128 + c)) * HWSZ + p];
    z[idx] = gelu_f(a[idx]) * g;
}

// ---------------- K6: out(B,HW,32) = z(B,128,HW)^T @ w2(128,32) + b2
__global__ __launch_bounds__(256) void k6_fc2(const float* __restrict__ z,
                                              const float* __restrict__ w2,
                                              const float* __restrict__ b2,
                                              float* __restrict__ out) {
    int idx = blockIdx.x * 256 + threadIdx.x;  // (b,p,d)
    int d = idx & 31;
    int p = (idx >> 5) & 4095;
    int b = idx >> 17;
    const float* zb = z + (size_t)b * 128 * HWSZ;
    float acc = b2[d];
    for (int c = 0; c < 128; ++c) acc = fmaf(zb[c * HWSZ + p], w2[c * 32 + d], acc);
    out[idx] = acc;
}

extern "C" void kernel_launch(void* const* d_in, const int* in_sizes, int n_in,
                              void* d_out, int out_size, void* d_ws, size_t ws_size,
                              hipStream_t stream) {
    const float* x   = (const float*)d_in[0];
    const float* w1  = (const float*)d_in[1];
    const float* b1  = (const float*)d_in[2];
    const float* dww = (const float*)d_in[3];
    const float* dwb = (const float*)d_in[4];
    const float* pww = (const float*)d_in[5];
    const float* pwb = (const float*)d_in[6];
    const float* o3w = (const float*)d_in[7];
    const float* o3b = (const float*)d_in[8];
    const float* d3w = (const float*)d_in[9];
    const float* d3b = (const float*)d_in[10];
    const float* o4w = (const float*)d_in[11];
    const float* o4b = (const float*)d_in[12];
    const float* d4w = (const float*)d_in[13];
    const float* d4b = (const float*)d_in[14];
    const float* o5w = (const float*)d_in[15];
    const float* o5b = (const float*)d_in[16];
    const float* d5w = (const float*)d_in[17];
    const float* d5b = (const float*)d_in[18];
    const float* w2  = (const float*)d_in[19];
    const float* b2  = (const float*)d_in[20];

    float* ws = (float*)d_ws;
    float* xi   = ws;                    // 1,048,576 f32
    float* dwo  = ws + 1048576;          // 1,048,576 f32
    float* y    = ws + 2097152;          // 2,097,152 f32
    float* a5   = ws + 4194304;          // 1,048,576 f32
    float* z    = ws + 5242880;          // 1,048,576 f32
    float* offb = ws + 6291456;          // up to 1,048,576 f32 (used <= 2*112*4096)
    _Float16* clA = (_Float16*)(ws + 7340032);  // 1,290,240 f16
    _Float16* clB = (_Float16*)(ws + 7985152);  // 1,290,240 f16
    _Float16* wA3 = (_Float16*)(ws + 8630272);  // 49*112*128
    _Float16* wA4 = (_Float16*)(ws + 8981504);  // 9*32*128
    _Float16* wA5 = (_Float16*)(ws + 8999936);  // 25*64*128
    _Float16* wM3 = (_Float16*)(ws + 9102336);  // 49*128*128
    _Float16* wM4 = (_Float16*)(ws + 9503744);  // 9*128*128
    _Float16* wM5 = (_Float16*)(ws + 9577472);  // 25*128*128

    // front of net
    k1_fc1<<<4096, 256, 0, stream>>>(x, w1, b1, xi);
    k2_dw<<<4096, 256, 0, stream>>>(xi, dww, dwb, dwo);
    k3_pw<<<8192, 256, 0, stream>>>(dwo, pww, pwb, y);

    // weight transforms (f16, scaled)
    wtr<<<2744, 256, 0, stream>>>(o3w, wA3, 49, 112, 98, 256.f);
    wtr<<<144,  256, 0, stream>>>(o4w, wA4, 9,  32,  18, 256.f);
    wtr<<<800,  256, 0, stream>>>(o5w, wA5, 25, 64,  50, 256.f);
    wtr<<<3136, 256, 0, stream>>>(d3w, wM3, 49, 128, 128, 16.f);
    wtr<<<576,  256, 0, stream>>>(d4w, wM4, 9,  128, 128, 16.f);
    wtr<<<1600, 256, 0, stream>>>(d5w, wM5, 25, 128, 128, 16.f);

    // channels-last staging
    zcl<<<2520, 256, 0, stream>>>((unsigned int*)clB);  // 645,120 uints
    p1_cl<<<5040, 256, 0, stream>>>(y, clA);            // d3 input (y[:, :128])

    // d3: k=7, pad=3, T=49, off OCp=112 (MT=7)
    k4G<7, 7, 3, 49><<<128, 256, 0, stream>>>(clA, wA3, o3b, offb, 98);
    k5G<7, 3, 49, 0><<<128, 256, 0, stream>>>(clA, offb, 112, wM3, d3b, nullptr, clB);

    // d4: k=3, pad=1, T=9, off OCp=32 (MT=2)
    k4G<2, 3, 1, 9><<<128, 256, 0, stream>>>(clB, wA4, o4b, offb, 18);
    k5G<3, 1, 9, 0><<<128, 256, 0, stream>>>(clB, offb, 32, wM4, d4b, nullptr, clA);

    // d5: k=5, pad=2, T=25, off OCp=64 (MT=4) -> channels-first f32
    k4G<4, 5, 2, 25><<<128, 256, 0, stream>>>(clA, wA5, o5b, offb, 50);
    k5G<5, 2, 25, 1><<<128, 256, 0, stream>>>(clA, offb, 64, wM5, d5b, a5, nullptr);

    // tail
    kz<<<4096, 256, 0, stream>>>(a5, y, z);
    k6_fc2<<<1024, 256, 0, stream>>>(z, w2, b2, (float*)d_out);
}

// Round 3
// 558.029 us; speedup vs baseline: 6.2131x; 1.5761x over previous
//
#include <hip/hip_runtime.h>
#include <hip/hip_bf16.h>

// Shapes: B=2, H=W=64, HW=4096, DIM=32, HID=128
#define HWSZ 4096

typedef _Float16 half8 __attribute__((ext_vector_type(8)));
typedef _Float16 half4 __attribute__((ext_vector_type(4)));
typedef float f32x4 __attribute__((ext_vector_type(4)));

__device__ __forceinline__ float gelu_f(float v) {
    return 0.5f * v * (1.0f + erff(v * 0.7071067811865475f));
}

// ---------------- K1: x(B,HW,32) @ w1(32,128) + b1, gelu, store channels-first (B,128,HW)
__global__ __launch_bounds__(256) void k1_fc1(const float* __restrict__ x,
                                              const float* __restrict__ w1,
                                              const float* __restrict__ b1,
                                              float* __restrict__ xi) {
    int idx = blockIdx.x * 256 + threadIdx.x;  // (b,c,p)
    int p = idx & 4095;
    int c = (idx >> 12) & 127;
    int b = idx >> 19;
    const float* xr = x + (size_t)(b * HWSZ + p) * 32;
    float acc = b1[c];
#pragma unroll
    for (int k = 0; k < 32; ++k) acc = fmaf(xr[k], w1[k * 128 + c], acc);
    xi[idx] = gelu_f(acc);
}

// ---------------- K2: depthwise 3x3 (pad 1), + bias
__global__ __launch_bounds__(256) void k2_dw(const float* __restrict__ xi,
                                             const float* __restrict__ dww,
                                             const float* __restrict__ dwb,
                                             float* __restrict__ dwo) {
    int idx = blockIdx.x * 256 + threadIdx.x;  // (b,c,p)
    int p = idx & 4095;
    int c = (idx >> 12) & 127;
    int h = p >> 6, w = p & 63;
    const float* plane = xi + (size_t)(idx >> 12) * HWSZ;
    float acc = dwb[c];
    for (int i = 0; i < 3; ++i) {
        int y = h + i - 1;
        if (y < 0 || y > 63) continue;
        for (int j = 0; j < 3; ++j) {
            int xx = w + j - 1;
            if (xx < 0 || xx > 63) continue;
            acc = fmaf(plane[y * 64 + xx], dww[c * 9 + i * 3 + j], acc);
        }
    }
    dwo[idx] = acc;
}

// ---------------- K3: pointwise 128->256, + bias, gelu
__global__ __launch_bounds__(256) void k3_pw(const float* __restrict__ dwo,
                                             const float* __restrict__ pww,
                                             const float* __restrict__ pwb,
                                             float* __restrict__ y) {
    int idx = blockIdx.x * 256 + threadIdx.x;  // (b,o(256),p)
    int p = idx & 4095;
    int o = (idx >> 12) & 255;
    int b = idx >> 20;
    const float* din = dwo + (size_t)b * 128 * HWSZ;
    const float* wr = pww + o * 128;
    float acc = pwb[o];
    for (int c = 0; c < 128; ++c) acc = fmaf(din[c * HWSZ + p], wr[c], acc);
    y[idx] = gelu_f(acc);
}

// ---------------- zero a channels-last padded buffer (as uints)
__global__ __launch_bounds__(256) void zcl(unsigned int* __restrict__ p) {
    p[blockIdx.x * 256 + threadIdx.x] = 0u;
}

// ---------------- P1: y[:, :128] f32 channels-first -> clA (B,70,72,128) f16, zero halo
__global__ __launch_bounds__(256) void p1_cl(const float* __restrict__ y,
                                             _Float16* __restrict__ cl) {
    int idx = blockIdx.x * 256 + threadIdx.x;  // (b,hh,ww,c)
    int c = idx & 127;
    int t = idx >> 7;
    int ww = t % 72;
    int t2 = t / 72;
    int hh = t2 % 70;
    int b = t2 / 70;
    float v = 0.f;
    if (hh >= 3 && hh < 67 && ww >= 3 && ww < 67)
        v = y[((size_t)(b * 256 + c)) * HWSZ + (hh - 3) * 64 + (ww - 3)];
    cl[idx] = (_Float16)v;
}

// ---------------- weight transform: (O,128,T) f32 -> (T,Op,128) f16, scaled, zero-pad rows
__global__ __launch_bounds__(256) void wtr(const float* __restrict__ w,
                                           _Float16* __restrict__ o,
                                           int T, int Op, int O, float scale) {
    int idx = blockIdx.x * 256 + threadIdx.x;  // (t, op, c)
    int c = idx & 127;
    int op = (idx >> 7) % Op;
    int t = idx / (128 * Op);
    float v = (op < O) ? w[((size_t)(op * 128 + c)) * T + t] * scale : 0.f;
    o[idx] = (_Float16)v;
}

// ---------------- K4Gv2: offset conv as implicit-im2col MFMA GEMM, one M-tile per wave
// grid (128, MT); block 256 (4 waves x 16 px). cl padded CL f16; wA (T,OCp,128) x256.
template <int KK, int PAD, int T>
__global__ __launch_bounds__(256) void k4Gv2(const _Float16* __restrict__ cl,
                                             const _Float16* __restrict__ wA,
                                             const float* __restrict__ obias,
                                             float* __restrict__ offb,
                                             int OC, int OCp) {
    int tid = threadIdx.x;
    int wv = tid >> 6;
    int l = tid & 63;
    int col = l & 15, kg = l >> 4;
    int blk = blockIdx.x;
    int b = blk >> 6, h = blk & 63;
    int m = blockIdx.y;
    int px0 = wv * 16;
    f32x4 acc = (f32x4){0.f, 0.f, 0.f, 0.f};
    const _Float16* clb = cl + (size_t)b * 70 * 72 * 128;
    for (int t = 0; t < T; ++t) {
        int ky = t / KK, kx = t % KK;
        int hh = h + ky + (3 - PAD);
        int ww = px0 + col + kx + (3 - PAD);
        const _Float16* bp = clb + ((size_t)hh * 72 + ww) * 128 + kg * 8;
        const _Float16* ap = wA + ((size_t)t * OCp + m * 16 + col) * 128 + kg * 8;
#pragma unroll
        for (int cc = 0; cc < 4; ++cc) {
            half8 bf = *(const half8*)(bp + cc * 32);
            half8 af = *(const half8*)(ap + cc * 32);
            acc = __builtin_amdgcn_mfma_f32_16x16x32_f16(af, bf, acc, 0, 0, 0);
        }
    }
    int px = h * 64 + px0 + col;
#pragma unroll
    for (int r = 0; r < 4; ++r) {
        int oc = m * 16 + kg * 4 + r;
        float v = acc[r] * (1.0f / 256.0f) + (oc < OC ? obias[oc] : 0.f);
        offb[((size_t)(b * OCp + oc)) * HWSZ + px] = v;
    }
}

// ---------------- K5Gv2: deformable conv, LDS-shared sampled B panel, 8 M-waves
// grid 512; block 512. cl padded CL f16; offb (B,OFFP,4096) f32; wM (T,128,128) x16.
// MODE 0: write CL f16 padded interior (outH). MODE 1: write CF f32 (outF).
template <int KK, int PAD, int T, int MODE>
__global__ __launch_bounds__(512) void k5Gv2(const _Float16* __restrict__ cl,
                                             const float* __restrict__ offb, int OFFP,
                                             const _Float16* __restrict__ wM,
                                             const float* __restrict__ bias,
                                             float* __restrict__ outF,
                                             _Float16* __restrict__ outH) {
    __shared__ float pwS[T * 16 * 4];
    __shared__ int poS[T * 16 * 4];
    __shared__ _Float16 v16[16 * 128];
    int tid = threadIdx.x;
    int blk = blockIdx.x;
    int b = blk >> 8;
    int px0 = (blk & 255) << 4;  // 16 consecutive pixels, same h row
    const _Float16* clb = cl + (size_t)b * 70 * 72 * 128;
    const float* ob = offb + (size_t)b * OFFP * HWSZ;

    // ---- precompute all bilinear params for 16 px x T taps
    for (int q = tid; q < T * 16; q += 512) {
        int t = q >> 4, i = q & 15;
        int p = px0 + i, h = p >> 6, w = p & 63;
        int ky = t / KK, kx = t % KK;
        float dy = ob[(size_t)(2 * t) * HWSZ + p];
        float dx = ob[(size_t)(2 * t + 1) * HWSZ + p];
        float py = (float)(h + ky - PAD) + dy;
        float pxs = (float)(w + kx - PAD) + dx;
        float y0f = floorf(py), x0f = floorf(pxs);
        float wy = py - y0f, wx = pxs - x0f;
        int y0 = (int)y0f, x0 = (int)x0f;
        int y1 = y0 + 1, x1 = x0 + 1;
        bool vy0 = (y0 >= 0) && (y0 < 64), vy1 = (y1 >= 0) && (y1 < 64);
        bool vx0 = (x0 >= 0) && (x0 < 64), vx1 = (x1 >= 0) && (x1 < 64);
        int cy0 = min(max(y0, 0), 63) + 3, cy1 = min(max(y1, 0), 63) + 3;
        int cx0 = min(max(x0, 0), 63) + 3, cx1 = min(max(x1, 0), 63) + 3;
        pwS[q * 4 + 0] = (vy0 && vx0) ? (1.f - wy) * (1.f - wx) : 0.f;
        pwS[q * 4 + 1] = (vy0 && vx1) ? (1.f - wy) * wx : 0.f;
        pwS[q * 4 + 2] = (vy1 && vx0) ? wy * (1.f - wx) : 0.f;
        pwS[q * 4 + 3] = (vy1 && vx1) ? wy * wx : 0.f;
        poS[q * 4 + 0] = (cy0 * 72 + cx0) * 128;
        poS[q * 4 + 1] = (cy0 * 72 + cx1) * 128;
        poS[q * 4 + 2] = (cy1 * 72 + cx0) * 128;
        poS[q * 4 + 3] = (cy1 * 72 + cx1) * 128;
    }
    __syncthreads();

    int wv = tid >> 6;             // wave -> M tile (0..7)
    int l = tid & 63;
    int col = l & 15, kg = l >> 4;
    int i_s = tid >> 5;            // sampling pixel 0..15
    int sub = tid & 31;            // channel quad 0..31 (4 channels each)
    int c0 = sub * 4;
    int slot = sub >> 1;
    f32x4 acc = (f32x4){0.f, 0.f, 0.f, 0.f};

    for (int t = 0; t < T; ++t) {
        // ---- sample 16 px x 128 ch into swizzled LDS panel
        int q = (t * 16 + i_s) * 4;
        float w00 = pwS[q + 0], w01 = pwS[q + 1], w10 = pwS[q + 2], w11 = pwS[q + 3];
        half4 a00 = *(const half4*)(clb + poS[q + 0] + c0);
        half4 a01 = *(const half4*)(clb + poS[q + 1] + c0);
        half4 a10 = *(const half4*)(clb + poS[q + 2] + c0);
        half4 a11 = *(const half4*)(clb + poS[q + 3] + c0);
        half4 r;
#pragma unroll
        for (int j = 0; j < 4; ++j) {
            float v = w00 * (float)a00[j] + w01 * (float)a01[j] +
                      w10 * (float)a10[j] + w11 * (float)a11[j];
            r[j] = (_Float16)v;
        }
        *(half4*)&v16[i_s * 128 + ((slot ^ (i_s & 7)) * 8) + (sub & 1) * 4] = r;
        __syncthreads();
        // ---- 4 MFMAs per wave against the shared panel
        const _Float16* ap = wM + ((size_t)t * 128 + wv * 16 + col) * 128 + kg * 8;
#pragma unroll
        for (int cc = 0; cc < 4; ++cc) {
            half8 bf = *(const half8*)&v16[col * 128 + (((cc * 4 + kg) ^ (col & 7)) * 8)];
            half8 af = *(const half8*)(ap + cc * 32);
            acc = __builtin_amdgcn_mfma_f32_16x16x32_f16(af, bf, acc, 0, 0, 0);
        }
        __syncthreads();
    }

    int p = px0 + col, h = p >> 6, w = p & 63;
    if (MODE == 1) {
#pragma unroll
        for (int r = 0; r < 4; ++r) {
            int oc = wv * 16 + kg * 4 + r;
            float v = gelu_f(acc[r] * (1.0f / 16.0f) + bias[oc]);
            outF[((size_t)(b * 128 + oc)) * HWSZ + p] = v;
        }
    } else {
        half4 t4;
#pragma unroll
        for (int r = 0; r < 4; ++r) {
            int oc = wv * 16 + kg * 4 + r;
            t4[r] = (_Float16)gelu_f(acc[r] * (1.0f / 16.0f) + bias[oc]);
        }
        _Float16* dst = outH + (size_t)b * 70 * 72 * 128 +
                        ((size_t)(h + 3) * 72 + (3 + w)) * 128 + wv * 16 + kg * 4;
        *(half4*)dst = t4;
    }
}

// ---------------- KZ: z = gelu(a) * g  (channels-first)
__global__ __launch_bounds__(256) void kz(const float* __restrict__ a,
                                          const float* __restrict__ y,
                                          float* __restrict__ z) {
    int idx = blockIdx.x * 256 + threadIdx.x;  // (b,c,p)
    int p = idx & 4095;
    int c = (idx >> 12) & 127;
    int b = idx >> 19;
    float g = y[((size_t)(b * 256 + 128 + c)) * HWSZ + p];
    z[idx] = gelu_f(a[idx]) * g;
}

// ---------------- K6: out(B,HW,32) = z(B,128,HW)^T @ w2(128,32) + b2
__global__ __launch_bounds__(256) void k6_fc2(const float* __restrict__ z,
                                              const float* __restrict__ w2,
                                              const float* __restrict__ b2,
                                              float* __restrict__ out) {
    int idx = blockIdx.x * 256 + threadIdx.x;  // (b,p,d)
    int d = idx & 31;
    int p = (idx >> 5) & 4095;
    int b = idx >> 17;
    const float* zb = z + (size_t)b * 128 * HWSZ;
    float acc = b2[d];
    for (int c = 0; c < 128; ++c) acc = fmaf(zb[c * HWSZ + p], w2[c * 32 + d], acc);
    out[idx] = acc;
}

extern "C" void kernel_launch(void* const* d_in, const int* in_sizes, int n_in,
                              void* d_out, int out_size, void* d_ws, size_t ws_size,
                              hipStream_t stream) {
    const float* x   = (const float*)d_in[0];
    const float* w1  = (const float*)d_in[1];
    const float* b1  = (const float*)d_in[2];
    const float* dww = (const float*)d_in[3];
    const float* dwb = (const float*)d_in[4];
    const float* pww = (const float*)d_in[5];
    const float* pwb = (const float*)d_in[6];
    const float* o3w = (const float*)d_in[7];
    const float* o3b = (const float*)d_in[8];
    const float* d3w = (const float*)d_in[9];
    const float* d3b = (const float*)d_in[10];
    const float* o4w = (const float*)d_in[11];
    const float* o4b = (const float*)d_in[12];
    const float* d4w = (const float*)d_in[13];
    const float* d4b = (const float*)d_in[14];
    const float* o5w = (const float*)d_in[15];
    const float* o5b = (const float*)d_in[16];
    const float* d5w = (const float*)d_in[17];
    const float* d5b = (const float*)d_in[18];
    const float* w2  = (const float*)d_in[19];
    const float* b2  = (const float*)d_in[20];

    float* ws = (float*)d_ws;
    float* xi   = ws;                    // 1,048,576 f32
    float* dwo  = ws + 1048576;          // 1,048,576 f32
    float* y    = ws + 2097152;          // 2,097,152 f32
    float* a5   = ws + 4194304;          // 1,048,576 f32
    float* z    = ws + 5242880;          // 1,048,576 f32
    float* offb = ws + 6291456;          // up to 1,048,576 f32 (used <= 2*112*4096)
    _Float16* clA = (_Float16*)(ws + 7340032);  // 1,290,240 f16
    _Float16* clB = (_Float16*)(ws + 7985152);  // 1,290,240 f16
    _Float16* wA3 = (_Float16*)(ws + 8630272);  // 49*112*128
    _Float16* wA4 = (_Float16*)(ws + 8981504);  // 9*32*128
    _Float16* wA5 = (_Float16*)(ws + 8999936);  // 25*64*128
    _Float16* wM3 = (_Float16*)(ws + 9102336);  // 49*128*128
    _Float16* wM4 = (_Float16*)(ws + 9503744);  // 9*128*128
    _Float16* wM5 = (_Float16*)(ws + 9577472);  // 25*128*128

    // front of net
    k1_fc1<<<4096, 256, 0, stream>>>(x, w1, b1, xi);
    k2_dw<<<4096, 256, 0, stream>>>(xi, dww, dwb, dwo);
    k3_pw<<<8192, 256, 0, stream>>>(dwo, pww, pwb, y);

    // weight transforms (f16, scaled)
    wtr<<<2744, 256, 0, stream>>>(o3w, wA3, 49, 112, 98, 256.f);
    wtr<<<144,  256, 0, stream>>>(o4w, wA4, 9,  32,  18, 256.f);
    wtr<<<800,  256, 0, stream>>>(o5w, wA5, 25, 64,  50, 256.f);
    wtr<<<3136, 256, 0, stream>>>(d3w, wM3, 49, 128, 128, 16.f);
    wtr<<<576,  256, 0, stream>>>(d4w, wM4, 9,  128, 128, 16.f);
    wtr<<<1600, 256, 0, stream>>>(d5w, wM5, 25, 128, 128, 16.f);

    // channels-last staging
    zcl<<<2520, 256, 0, stream>>>((unsigned int*)clB);  // 645,120 uints
    p1_cl<<<5040, 256, 0, stream>>>(y, clA);            // d3 input (y[:, :128])

    // d3: k=7, pad=3, T=49, off OCp=112 (7 M-tiles)
    k4Gv2<7, 3, 49><<<dim3(128, 7), 256, 0, stream>>>(clA, wA3, o3b, offb, 98, 112);
    k5Gv2<7, 3, 49, 0><<<512, 512, 0, stream>>>(clA, offb, 112, wM3, d3b, nullptr, clB);

    // d4: k=3, pad=1, T=9, off OCp=32 (2 M-tiles)
    k4Gv2<3, 1, 9><<<dim3(128, 2), 256, 0, stream>>>(clB, wA4, o4b, offb, 18, 32);
    k5Gv2<3, 1, 9, 0><<<512, 512, 0, stream>>>(clB, offb, 32, wM4, d4b, nullptr, clA);

    // d5: k=5, pad=2, T=25, off OCp=64 (4 M-tiles) -> channels-first f32
    k4Gv2<5, 2, 25><<<dim3(128, 4), 256, 0, stream>>>(clA, wA5, o5b, offb, 50, 64);
    k5Gv2<5, 2, 25, 1><<<512, 512, 0, stream>>>(clA, offb, 64, wM5, d5b, a5, nullptr);

    // tail
    kz<<<4096, 256, 0, stream>>>(a5, y, z);
    k6_fc2<<<1024, 256, 0, stream>>>(z, w2, b2, (float*)d_out);
}

// Round 4
// 415.104 us; speedup vs baseline: 8.3524x; 1.3443x over previous
//
#include <hip/hip_runtime.h>
#include <hip/hip_bf16.h>

// Shapes: B=2, H=W=64, HW=4096, DIM=32, HID=128
#define HWSZ 4096

typedef _Float16 half8 __attribute__((ext_vector_type(8)));
typedef _Float16 half4 __attribute__((ext_vector_type(4)));
typedef float f32x4 __attribute__((ext_vector_type(4)));

__device__ __forceinline__ float gelu_f(float v) {
    return 0.5f * v * (1.0f + erff(v * 0.7071067811865475f));
}

// ---------------- K1: x(B,HW,32) @ w1(32,128) + b1, gelu, store channels-first (B,128,HW)
__global__ __launch_bounds__(256) void k1_fc1(const float* __restrict__ x,
                                              const float* __restrict__ w1,
                                              const float* __restrict__ b1,
                                              float* __restrict__ xi) {
    int idx = blockIdx.x * 256 + threadIdx.x;  // (b,c,p)
    int p = idx & 4095;
    int c = (idx >> 12) & 127;
    int b = idx >> 19;
    const float* xr = x + (size_t)(b * HWSZ + p) * 32;
    float acc = b1[c];
#pragma unroll
    for (int k = 0; k < 32; ++k) acc = fmaf(xr[k], w1[k * 128 + c], acc);
    xi[idx] = gelu_f(acc);
}

// ---------------- K2: depthwise 3x3 (pad 1), + bias
__global__ __launch_bounds__(256) void k2_dw(const float* __restrict__ xi,
                                             const float* __restrict__ dww,
                                             const float* __restrict__ dwb,
                                             float* __restrict__ dwo) {
    int idx = blockIdx.x * 256 + threadIdx.x;  // (b,c,p)
    int p = idx & 4095;
    int c = (idx >> 12) & 127;
    int h = p >> 6, w = p & 63;
    const float* plane = xi + (size_t)(idx >> 12) * HWSZ;
    float acc = dwb[c];
    for (int i = 0; i < 3; ++i) {
        int y = h + i - 1;
        if (y < 0 || y > 63) continue;
        for (int j = 0; j < 3; ++j) {
            int xx = w + j - 1;
            if (xx < 0 || xx > 63) continue;
            acc = fmaf(plane[y * 64 + xx], dww[c * 9 + i * 3 + j], acc);
        }
    }
    dwo[idx] = acc;
}

// ---------------- K3: pointwise 128->256, + bias, gelu
__global__ __launch_bounds__(256) void k3_pw(const float* __restrict__ dwo,
                                             const float* __restrict__ pww,
                                             const float* __restrict__ pwb,
                                             float* __restrict__ y) {
    int idx = blockIdx.x * 256 + threadIdx.x;  // (b,o(256),p)
    int p = idx & 4095;
    int o = (idx >> 12) & 255;
    int b = idx >> 20;
    const float* din = dwo + (size_t)b * 128 * HWSZ;
    const float* wr = pww + o * 128;
    float acc = pwb[o];
    for (int c = 0; c < 128; ++c) acc = fmaf(din[c * HWSZ + p], wr[c], acc);
    y[idx] = gelu_f(acc);
}

// ---------------- zero a channels-last padded buffer (as uints)
__global__ __launch_bounds__(256) void zcl(unsigned int* __restrict__ p) {
    p[blockIdx.x * 256 + threadIdx.x] = 0u;
}

// ---------------- P1: y[:, :128] f32 channels-first -> clA (B,70,72,128) f16, zero halo
__global__ __launch_bounds__(256) void p1_cl(const float* __restrict__ y,
                                             _Float16* __restrict__ cl) {
    int idx = blockIdx.x * 256 + threadIdx.x;  // (b,hh,ww,c)
    int c = idx & 127;
    int t = idx >> 7;
    int ww = t % 72;
    int t2 = t / 72;
    int hh = t2 % 70;
    int b = t2 / 70;
    float v = 0.f;
    if (hh >= 3 && hh < 67 && ww >= 3 && ww < 67)
        v = y[((size_t)(b * 256 + c)) * HWSZ + (hh - 3) * 64 + (ww - 3)];
    cl[idx] = (_Float16)v;
}

// ---------------- weight transform: (O,128,T) f32 -> (T,Op,128) f16, scaled, zero-pad rows
__global__ __launch_bounds__(256) void wtr(const float* __restrict__ w,
                                           _Float16* __restrict__ o,
                                           int T, int Op, int O, float scale) {
    int idx = blockIdx.x * 256 + threadIdx.x;  // (t, op, c)
    int c = idx & 127;
    int op = (idx >> 7) % Op;
    int t = idx / (128 * Op);
    float v = (op < O) ? w[((size_t)(op * 128 + c)) * T + t] * scale : 0.f;
    o[idx] = (_Float16)v;
}

// ---------------- K4Gv3: offset conv = implicit-im2col MFMA GEMM with LDS-staged B
// Block = 512 thr = 8 waves; wave wv -> m-tile (wv%MT), n-group (wv/MT) of NA*16 px.
// B window (KK rows x COLS px x 128ch) staged to LDS once, XOR-swizzled.
// A (weights) double-buffered in registers across the tap loop.
template <int KK, int PAD, int T, int MT, int NG, int NA, int WPX>
__global__ __launch_bounds__(512) void k4Gv3(const _Float16* __restrict__ cl,
                                             const _Float16* __restrict__ wA,
                                             const float* __restrict__ obias,
                                             float* __restrict__ offb, int OC) {
    constexpr int OCp = MT * 16;
    constexpr int COLS = WPX + KK - 1;
    constexpr int NB = 64 / WPX;  // w0 positions per row
    __shared__ _Float16 bS[KK * COLS * 128];

    int tid = threadIdx.x;
    int blk = blockIdx.x;
    int w0 = (blk % NB) * WPX;
    int h = (blk / NB) & 63;
    int b = blk / (NB * 64);
    const _Float16* clb = cl + (size_t)b * 70 * 72 * 128;

    // ---- stage B window
    int hh0 = h + (3 - PAD);
    int ww0 = w0 + (3 - PAD);
    for (int g = tid; g < KK * COLS * 16; g += 512) {
        int r = g / (COLS * 16);
        int rest = g - r * (COLS * 16);
        int c = rest >> 4;
        int s = rest & 15;
        half8 v = *(const half8*)(clb + ((size_t)(hh0 + r) * 72 + (ww0 + c)) * 128 + s * 8);
        *(half8*)&bS[((r * COLS + c) * 16 + (s ^ (c & 7))) * 8] = v;
    }

    int wv = tid >> 6;
    int l = tid & 63;
    int col = l & 15, kg = l >> 4;
    int m = wv % MT;
    int ng = wv / MT;

    const _Float16* apbase = wA + ((size_t)(m * 16 + col)) * 128 + kg * 8;
    half8 afv[4];
#pragma unroll
    for (int cc = 0; cc < 4; ++cc) afv[cc] = *(const half8*)(apbase + cc * 32);

    f32x4 acc[NA];
#pragma unroll
    for (int a = 0; a < NA; ++a) acc[a] = (f32x4){0.f, 0.f, 0.f, 0.f};

    __syncthreads();

    for (int t = 0; t < T; ++t) {
        int ky = t / KK, kx = t - ky * KK;
        half8 afn[4];
        if (t + 1 < T) {
            const _Float16* apn = apbase + (size_t)(t + 1) * OCp * 128;
#pragma unroll
            for (int cc = 0; cc < 4; ++cc) afn[cc] = *(const half8*)(apn + cc * 32);
        }
#pragma unroll
        for (int a = 0; a < NA; ++a) {
            int cw = ng * NA * 16 + a * 16 + col + kx;
#pragma unroll
            for (int cc = 0; cc < 4; ++cc) {
                half8 bf = *(const half8*)&bS[((ky * COLS + cw) * 16 + ((cc * 4 + kg) ^ (cw & 7))) * 8];
                acc[a] = __builtin_amdgcn_mfma_f32_16x16x32_f16(afv[cc], bf, acc[a], 0, 0, 0);
            }
        }
#pragma unroll
        for (int cc = 0; cc < 4; ++cc) afv[cc] = afn[cc];
    }

#pragma unroll
    for (int a = 0; a < NA; ++a) {
        int px = h * 64 + w0 + ng * NA * 16 + a * 16 + col;
#pragma unroll
        for (int r = 0; r < 4; ++r) {
            int oc = m * 16 + kg * 4 + r;
            float v = acc[a][r] * (1.0f / 256.0f) + (oc < OC ? obias[oc] : 0.f);
            offb[((size_t)(b * OCp + oc)) * HWSZ + px] = v;
        }
    }
}

// ---------------- K5Gv2: deformable conv, LDS-shared sampled B panel, 8 M-waves
// grid 512; block 512. cl padded CL f16; offb (B,OFFP,4096) f32; wM (T,128,128) x16.
// MODE 0: write CL f16 padded interior (outH). MODE 1: write CF f32 (outF).
template <int KK, int PAD, int T, int MODE>
__global__ __launch_bounds__(512) void k5Gv2(const _Float16* __restrict__ cl,
                                             const float* __restrict__ offb, int OFFP,
                                             const _Float16* __restrict__ wM,
                                             const float* __restrict__ bias,
                                             float* __restrict__ outF,
                                             _Float16* __restrict__ outH) {
    __shared__ float pwS[T * 16 * 4];
    __shared__ int poS[T * 16 * 4];
    __shared__ _Float16 v16[16 * 128];
    int tid = threadIdx.x;
    int blk = blockIdx.x;
    int b = blk >> 8;
    int px0 = (blk & 255) << 4;  // 16 consecutive pixels, same h row
    const _Float16* clb = cl + (size_t)b * 70 * 72 * 128;
    const float* ob = offb + (size_t)b * OFFP * HWSZ;

    // ---- precompute all bilinear params for 16 px x T taps
    for (int q = tid; q < T * 16; q += 512) {
        int t = q >> 4, i = q & 15;
        int p = px0 + i, h = p >> 6, w = p & 63;
        int ky = t / KK, kx = t % KK;
        float dy = ob[(size_t)(2 * t) * HWSZ + p];
        float dx = ob[(size_t)(2 * t + 1) * HWSZ + p];
        float py = (float)(h + ky - PAD) + dy;
        float pxs = (float)(w + kx - PAD) + dx;
        float y0f = floorf(py), x0f = floorf(pxs);
        float wy = py - y0f, wx = pxs - x0f;
        int y0 = (int)y0f, x0 = (int)x0f;
        int y1 = y0 + 1, x1 = x0 + 1;
        bool vy0 = (y0 >= 0) && (y0 < 64), vy1 = (y1 >= 0) && (y1 < 64);
        bool vx0 = (x0 >= 0) && (x0 < 64), vx1 = (x1 >= 0) && (x1 < 64);
        int cy0 = min(max(y0, 0), 63) + 3, cy1 = min(max(y1, 0), 63) + 3;
        int cx0 = min(max(x0, 0), 63) + 3, cx1 = min(max(x1, 0), 63) + 3;
        pwS[q * 4 + 0] = (vy0 && vx0) ? (1.f - wy) * (1.f - wx) : 0.f;
        pwS[q * 4 + 1] = (vy0 && vx1) ? (1.f - wy) * wx : 0.f;
        pwS[q * 4 + 2] = (vy1 && vx0) ? wy * (1.f - wx) : 0.f;
        pwS[q * 4 + 3] = (vy1 && vx1) ? wy * wx : 0.f;
        poS[q * 4 + 0] = (cy0 * 72 + cx0) * 128;
        poS[q * 4 + 1] = (cy0 * 72 + cx1) * 128;
        poS[q * 4 + 2] = (cy1 * 72 + cx0) * 128;
        poS[q * 4 + 3] = (cy1 * 72 + cx1) * 128;
    }
    __syncthreads();

    int wv = tid >> 6;             // wave -> M tile (0..7)
    int l = tid & 63;
    int col = l & 15, kg = l >> 4;
    int i_s = tid >> 5;            // sampling pixel 0..15
    int sub = tid & 31;            // channel quad 0..31 (4 channels each)
    int c0 = sub * 4;
    int slot = sub >> 1;
    f32x4 acc = (f32x4){0.f, 0.f, 0.f, 0.f};

    for (int t = 0; t < T; ++t) {
        // ---- sample 16 px x 128 ch into swizzled LDS panel
        int q = (t * 16 + i_s) * 4;
        float w00 = pwS[q + 0], w01 = pwS[q + 1], w10 = pwS[q + 2], w11 = pwS[q + 3];
        half4 a00 = *(const half4*)(clb + poS[q + 0] + c0);
        half4 a01 = *(const half4*)(clb + poS[q + 1] + c0);
        half4 a10 = *(const half4*)(clb + poS[q + 2] + c0);
        half4 a11 = *(const half4*)(clb + poS[q + 3] + c0);
        half4 r;
#pragma unroll
        for (int j = 0; j < 4; ++j) {
            float v = w00 * (float)a00[j] + w01 * (float)a01[j] +
                      w10 * (float)a10[j] + w11 * (float)a11[j];
            r[j] = (_Float16)v;
        }
        *(half4*)&v16[i_s * 128 + ((slot ^ (i_s & 7)) * 8) + (sub & 1) * 4] = r;
        __syncthreads();
        // ---- 4 MFMAs per wave against the shared panel
        const _Float16* ap = wM + ((size_t)t * 128 + wv * 16 + col) * 128 + kg * 8;
#pragma unroll
        for (int cc = 0; cc < 4; ++cc) {
            half8 bf = *(const half8*)&v16[col * 128 + (((cc * 4 + kg) ^ (col & 7)) * 8)];
            half8 af = *(const half8*)(ap + cc * 32);
            acc = __builtin_amdgcn_mfma_f32_16x16x32_f16(af, bf, acc, 0, 0, 0);
        }
        __syncthreads();
    }

    int p = px0 + col, h = p >> 6, w = p & 63;
    if (MODE == 1) {
#pragma unroll
        for (int r = 0; r < 4; ++r) {
            int oc = wv * 16 + kg * 4 + r;
            float v = gelu_f(acc[r] * (1.0f / 16.0f) + bias[oc]);
            outF[((size_t)(b * 128 + oc)) * HWSZ + p] = v;
        }
    } else {
        half4 t4;
#pragma unroll
        for (int r = 0; r < 4; ++r) {
            int oc = wv * 16 + kg * 4 + r;
            t4[r] = (_Float16)gelu_f(acc[r] * (1.0f / 16.0f) + bias[oc]);
        }
        _Float16* dst = outH + (size_t)b * 70 * 72 * 128 +
                        ((size_t)(h + 3) * 72 + (3 + w)) * 128 + wv * 16 + kg * 4;
        *(half4*)dst = t4;
    }
}

// ---------------- KZ: z = gelu(a) * g  (channels-first)
__global__ __launch_bounds__(256) void kz(const float* __restrict__ a,
                                          const float* __restrict__ y,
                                          float* __restrict__ z) {
    int idx = blockIdx.x * 256 + threadIdx.x;  // (b,c,p)
    int p = idx & 4095;
    int c = (idx >> 12) & 127;
    int b = idx >> 19;
    float g = y[((size_t)(b * 256 + 128 + c)) * HWSZ + p];
    z[idx] = gelu_f(a[idx]) * g;
}

// ---------------- K6: out(B,HW,32) = z(B,128,HW)^T @ w2(128,32) + b2
__global__ __launch_bounds__(256) void k6_fc2(const float* __restrict__ z,
                                              const float* __restrict__ w2,
                                              const float* __restrict__ b2,
                                              float* __restrict__ out) {
    int idx = blockIdx.x * 256 + threadIdx.x;  // (b,p,d)
    int d = idx & 31;
    int p = (idx >> 5) & 4095;
    int b = idx >> 17;
    const float* zb = z + (size_t)b * 128 * HWSZ;
    float acc = b2[d];
    for (int c = 0; c < 128; ++c) acc = fmaf(zb[c * HWSZ + p], w2[c * 32 + d], acc);
    out[idx] = acc;
}

extern "C" void kernel_launch(void* const* d_in, const int* in_sizes, int n_in,
                              void* d_out, int out_size, void* d_ws, size_t ws_size,
                              hipStream_t stream) {
    const float* x   = (const float*)d_in[0];
    const float* w1  = (const float*)d_in[1];
    const float* b1  = (const float*)d_in[2];
    const float* dww = (const float*)d_in[3];
    const float* dwb = (const float*)d_in[4];
    const float* pww = (const float*)d_in[5];
    const float* pwb = (const float*)d_in[6];
    const float* o3w = (const float*)d_in[7];
    const float* o3b = (const float*)d_in[8];
    const float* d3w = (const float*)d_in[9];
    const float* d3b = (const float*)d_in[10];
    const float* o4w = (const float*)d_in[11];
    const float* o4b = (const float*)d_in[12];
    const float* d4w = (const float*)d_in[13];
    const float* d4b = (const float*)d_in[14];
    const float* o5w = (const float*)d_in[15];
    const float* o5b = (const float*)d_in[16];
    const float* d5w = (const float*)d_in[17];
    const float* d5b = (const float*)d_in[18];
    const float* w2  = (const float*)d_in[19];
    const float* b2  = (const float*)d_in[20];

    float* ws = (float*)d_ws;
    float* xi   = ws;                    // 1,048,576 f32 (k1->k2; later reused as a5)
    float* dwo  = ws + 1048576;          // 1,048,576 f32 (k2->k3; later reused as z)
    float* y    = ws + 2097152;          // 2,097,152 f32
    float* a5   = xi;                    // alias (xi dead after k2)
    float* z    = dwo;                   // alias (dwo dead after k3)
    float* offb = ws + 4194304;          // 1,048,576 f32 (max 2*128*4096)
    _Float16* clA = (_Float16*)(ws + 5242880);  // 1,290,240 f16
    _Float16* clB = (_Float16*)(ws + 5888000);  // 1,290,240 f16
    _Float16* wA3 = (_Float16*)(ws + 6533120);  // 49*128*128 f16
    _Float16* wA4 = (_Float16*)(ws + 6934528);  // 9*32*128
    _Float16* wA5 = (_Float16*)(ws + 6952960);  // 25*64*128
    _Float16* wM3 = (_Float16*)(ws + 7055360);  // 49*128*128
    _Float16* wM4 = (_Float16*)(ws + 7456768);  // 9*128*128
    _Float16* wM5 = (_Float16*)(ws + 7530496);  // 25*128*128

    // front of net
    k1_fc1<<<4096, 256, 0, stream>>>(x, w1, b1, xi);
    k2_dw<<<4096, 256, 0, stream>>>(xi, dww, dwb, dwo);
    k3_pw<<<8192, 256, 0, stream>>>(dwo, pww, pwb, y);

    // weight transforms (f16, scaled)
    wtr<<<3136, 256, 0, stream>>>(o3w, wA3, 49, 128, 98, 256.f);
    wtr<<<144,  256, 0, stream>>>(o4w, wA4, 9,  32,  18, 256.f);
    wtr<<<800,  256, 0, stream>>>(o5w, wA5, 25, 64,  50, 256.f);
    wtr<<<3136, 256, 0, stream>>>(d3w, wM3, 49, 128, 128, 16.f);
    wtr<<<576,  256, 0, stream>>>(d4w, wM4, 9,  128, 128, 16.f);
    wtr<<<1600, 256, 0, stream>>>(d5w, wM5, 25, 128, 128, 16.f);

    // channels-last staging
    zcl<<<2520, 256, 0, stream>>>((unsigned int*)clB);  // 645,120 uints
    p1_cl<<<5040, 256, 0, stream>>>(y, clA);            // d3 input (y[:, :128])

    // d3: k=7, pad=3, T=49; off M padded 98->128 (MT=8, NA=2, WPX=32)
    k4Gv3<7, 3, 49, 8, 1, 2, 32><<<256, 512, 0, stream>>>(clA, wA3, o3b, offb, 98);
    k5Gv2<7, 3, 49, 0><<<512, 512, 0, stream>>>(clA, offb, 128, wM3, d3b, nullptr, clB);

    // d4: k=3, pad=1, T=9; OCp=32 (MT=2, NG=4, NA=1, WPX=64)
    k4Gv3<3, 1, 9, 2, 4, 1, 64><<<128, 512, 0, stream>>>(clB, wA4, o4b, offb, 18);
    k5Gv2<3, 1, 9, 0><<<512, 512, 0, stream>>>(clB, offb, 32, wM4, d4b, nullptr, clA);

    // d5: k=5, pad=2, T=25; OCp=64 (MT=4, NG=2, NA=1, WPX=32) -> CF f32 out
    k4Gv3<5, 2, 25, 4, 2, 1, 32><<<256, 512, 0, stream>>>(clA, wA5, o5b, offb, 50);
    k5Gv2<5, 2, 25, 1><<<512, 512, 0, stream>>>(clA, offb, 64, wM5, d5b, a5, nullptr);

    // tail
    kz<<<4096, 256, 0, stream>>>(a5, y, z);
    k6_fc2<<<1024, 256, 0, stream>>>(z, w2, b2, (float*)d_out);
}

// Round 5
// 338.605 us; speedup vs baseline: 10.2394x; 1.2259x over previous
//
#include <hip/hip_runtime.h>
#include <hip/hip_bf16.h>

// Shapes: B=2, H=W=64, HW=4096, DIM=32, HID=128
#define HWSZ 4096

typedef _Float16 half8 __attribute__((ext_vector_type(8)));
typedef _Float16 half4 __attribute__((ext_vector_type(4)));
typedef float f32x4 __attribute__((ext_vector_type(4)));

__device__ __forceinline__ float gelu_f(float v) {
    return 0.5f * v * (1.0f + erff(v * 0.7071067811865475f));
}

// ---------------- K1: x(B,HW,32) @ w1(32,128) + b1, gelu -> CL f16 (B,HW,128)
__global__ __launch_bounds__(256) void k1_cl(const float* __restrict__ x,
                                             const float* __restrict__ w1,
                                             const float* __restrict__ b1,
                                             _Float16* __restrict__ xicl) {
    int idx = blockIdx.x * 256 + threadIdx.x;  // (b,p,c)
    int c = idx & 127;
    int p = (idx >> 7) & 4095;
    int b = idx >> 19;
    const float* xr = x + (size_t)(b * HWSZ + p) * 32;
    float acc = b1[c];
#pragma unroll
    for (int k = 0; k < 32; ++k) acc = fmaf(xr[k], w1[k * 128 + c], acc);
    xicl[idx] = (_Float16)gelu_f(acc);
}

// ---------------- dwt transform: dww (128,1,3,3) f32 -> (9,128) f16
__global__ __launch_bounds__(256) void dwtk(const float* __restrict__ dww,
                                            _Float16* __restrict__ dwt) {
    int idx = blockIdx.x * 256 + threadIdx.x;
    if (idx >= 9 * 128) return;
    int c = idx & 127, j = idx >> 7;
    dwt[j * 128 + c] = (_Float16)dww[c * 9 + j];
}

// ---------------- pwt cast: pww (256,128) f32 -> f16 same layout
__global__ __launch_bounds__(256) void pcast(const float* __restrict__ pww,
                                             _Float16* __restrict__ pwt) {
    int idx = blockIdx.x * 256 + threadIdx.x;  // 32768
    pwt[idx] = (_Float16)pww[idx];
}

// ---------------- K2: depthwise 3x3 (pad 1) + bias, CL f16 in/out
__global__ __launch_bounds__(256) void k2_cl(const _Float16* __restrict__ xicl,
                                             const _Float16* __restrict__ dwt,
                                             const float* __restrict__ dwb,
                                             _Float16* __restrict__ dcl) {
    int idx = blockIdx.x * 256 + threadIdx.x;  // (b,p,cg)
    int cg = idx & 15;
    int p = (idx >> 4) & 4095;
    int b = idx >> 16;
    int h = p >> 6, w = p & 63;
    const _Float16* base = xicl + (size_t)b * HWSZ * 128;
    float acc[8];
#pragma unroll
    for (int j = 0; j < 8; ++j) acc[j] = 0.f;
#pragma unroll
    for (int i = 0; i < 3; ++i) {
        int y = h + i - 1;
        if ((unsigned)y > 63u) continue;
#pragma unroll
        for (int j2 = 0; j2 < 3; ++j2) {
            int xx = w + j2 - 1;
            if ((unsigned)xx > 63u) continue;
            half8 v = *(const half8*)(base + ((size_t)(y * 64 + xx)) * 128 + cg * 8);
            half8 wv8 = *(const half8*)(dwt + (i * 3 + j2) * 128 + cg * 8);
#pragma unroll
            for (int j = 0; j < 8; ++j) acc[j] = fmaf((float)v[j], (float)wv8[j], acc[j]);
        }
    }
    half8 o;
#pragma unroll
    for (int j = 0; j < 8; ++j) o[j] = (_Float16)(acc[j] + dwb[cg * 8 + j]);
    *(half8*)(dcl + ((size_t)(b * HWSZ) + p) * 128 + cg * 8) = o;
}

// ---------------- K3G: pointwise 128->256 MFMA GEMM + bias + gelu
// a-half -> clA padded interior f16; g-half -> gcl (B,HW,128) f16
__global__ __launch_bounds__(512) void k3G(const _Float16* __restrict__ dcl,
                                           const _Float16* __restrict__ pwt,
                                           const float* __restrict__ pwb,
                                           _Float16* __restrict__ clA,
                                           _Float16* __restrict__ gcl) {
    int tid = threadIdx.x;
    int wv = tid >> 6;
    int l = tid & 63;
    int col = l & 15, kg = l >> 4;
    int blk = blockIdx.x;
    int hf = blockIdx.y;  // 0:a 1:g
    int b = blk >> 8;
    int px0 = (blk & 255) << 4;
    int p = px0 + col;
    const _Float16* bp = dcl + ((size_t)(b * HWSZ) + p) * 128 + kg * 8;
    int oc0 = hf * 128 + wv * 16;
    const _Float16* ap = pwt + (size_t)(oc0 + col) * 128 + kg * 8;
    f32x4 acc = (f32x4){0.f, 0.f, 0.f, 0.f};
#pragma unroll
    for (int cc = 0; cc < 4; ++cc) {
        half8 bf = *(const half8*)(bp + cc * 32);
        half8 af = *(const half8*)(ap + cc * 32);
        acc = __builtin_amdgcn_mfma_f32_16x16x32_f16(af, bf, acc, 0, 0, 0);
    }
    int h = p >> 6, w = p & 63;
    half4 t4;
#pragma unroll
    for (int r = 0; r < 4; ++r) {
        int oc = oc0 + kg * 4 + r;
        t4[r] = (_Float16)gelu_f(acc[r] + pwb[oc]);
    }
    if (hf == 0) {
        _Float16* dst = clA + (size_t)b * 70 * 72 * 128 +
                        ((size_t)(h + 3) * 72 + (w + 3)) * 128 + wv * 16 + kg * 4;
        *(half4*)dst = t4;
    } else {
        *(half4*)(gcl + ((size_t)(b * HWSZ) + p) * 128 + wv * 16 + kg * 4) = t4;
    }
}

// ---------------- zero a channels-last padded buffer (as uints)
__global__ __launch_bounds__(256) void zcl(unsigned int* __restrict__ p) {
    p[blockIdx.x * 256 + threadIdx.x] = 0u;
}

// ---------------- weight transform: (O,128,T) f32 -> (T,Op,128) f16, scaled, zero-pad rows
__global__ __launch_bounds__(256) void wtr(const float* __restrict__ w,
                                           _Float16* __restrict__ o,
                                           int T, int Op, int O, float scale) {
    int idx = blockIdx.x * 256 + threadIdx.x;  // (t, op, c)
    int c = idx & 127;
    int op = (idx >> 7) % Op;
    int t = idx / (128 * Op);
    float v = (op < O) ? w[((size_t)(op * 128 + c)) * T + t] * scale : 0.f;
    o[idx] = (_Float16)v;
}

// ---------------- K4Gv3: offset conv = implicit-im2col MFMA GEMM with LDS-staged B
template <int KK, int PAD, int T, int MT, int NG, int NA, int WPX>
__global__ __launch_bounds__(512) void k4Gv3(const _Float16* __restrict__ cl,
                                             const _Float16* __restrict__ wA,
                                             const float* __restrict__ obias,
                                             float* __restrict__ offb, int OC) {
    constexpr int OCp = MT * 16;
    constexpr int COLS = WPX + KK - 1;
    constexpr int NB = 64 / WPX;  // w0 positions per row
    __shared__ _Float16 bS[KK * COLS * 128];

    int tid = threadIdx.x;
    int blk = blockIdx.x;
    int w0 = (blk % NB) * WPX;
    int h = (blk / NB) & 63;
    int b = blk / (NB * 64);
    const _Float16* clb = cl + (size_t)b * 70 * 72 * 128;

    int hh0 = h + (3 - PAD);
    int ww0 = w0 + (3 - PAD);
    for (int g = tid; g < KK * COLS * 16; g += 512) {
        int r = g / (COLS * 16);
        int rest = g - r * (COLS * 16);
        int c = rest >> 4;
        int s = rest & 15;
        half8 v = *(const half8*)(clb + ((size_t)(hh0 + r) * 72 + (ww0 + c)) * 128 + s * 8);
        *(half8*)&bS[((r * COLS + c) * 16 + (s ^ (c & 7))) * 8] = v;
    }

    int wv = tid >> 6;
    int l = tid & 63;
    int col = l & 15, kg = l >> 4;
    int m = wv % MT;
    int ng = wv / MT;

    const _Float16* apbase = wA + ((size_t)(m * 16 + col)) * 128 + kg * 8;
    half8 afv[4];
#pragma unroll
    for (int cc = 0; cc < 4; ++cc) afv[cc] = *(const half8*)(apbase + cc * 32);

    f32x4 acc[NA];
#pragma unroll
    for (int a = 0; a < NA; ++a) acc[a] = (f32x4){0.f, 0.f, 0.f, 0.f};

    __syncthreads();

    for (int t = 0; t < T; ++t) {
        int ky = t / KK, kx = t - ky * KK;
        half8 afn[4];
        if (t + 1 < T) {
            const _Float16* apn = apbase + (size_t)(t + 1) * OCp * 128;
#pragma unroll
            for (int cc = 0; cc < 4; ++cc) afn[cc] = *(const half8*)(apn + cc * 32);
        }
#pragma unroll
        for (int a = 0; a < NA; ++a) {
            int cw = ng * NA * 16 + a * 16 + col + kx;
#pragma unroll
            for (int cc = 0; cc < 4; ++cc) {
                half8 bf = *(const half8*)&bS[((ky * COLS + cw) * 16 + ((cc * 4 + kg) ^ (cw & 7))) * 8];
                acc[a] = __builtin_amdgcn_mfma_f32_16x16x32_f16(afv[cc], bf, acc[a], 0, 0, 0);
            }
        }
#pragma unroll
        for (int cc = 0; cc < 4; ++cc) afv[cc] = afn[cc];
    }

#pragma unroll
    for (int a = 0; a < NA; ++a) {
        int px = h * 64 + w0 + ng * NA * 16 + a * 16 + col;
#pragma unroll
        for (int r = 0; r < 4; ++r) {
            int oc = m * 16 + kg * 4 + r;
            float v = acc[a][r] * (1.0f / 256.0f) + (oc < OC ? obias[oc] : 0.f);
            offb[((size_t)(b * OCp + oc)) * HWSZ + px] = v;
        }
    }
}

// ---------------- K5Gv3: deformable conv, pair-pipelined, prefetched
// MODE 0: write CL f16 padded interior. MODE 2: write CL f16 flat (B,HW,128).
template <int KK, int PAD, int T, int MODE>
__global__ __launch_bounds__(512, 4) void k5Gv3(const _Float16* __restrict__ cl,
                                                const float* __restrict__ offb, int OFFP,
                                                const _Float16* __restrict__ wM,
                                                const float* __restrict__ bias,
                                                _Float16* __restrict__ outH) {
    constexpr int TP = (T + 1) & ~1;  // taps padded even
    constexpr int S = TP / 2;         // pairs
    __shared__ float pw4[4][TP * 16];
    __shared__ int po4[4][TP * 16];
    __shared__ _Float16 panel[2][2][16][128];  // [buf][tp][px][swizzled 16B slices]

    int tid = threadIdx.x;
    int blk = blockIdx.x;
    int b = blk >> 8;
    int px0 = (blk & 255) << 4;
    const _Float16* clb = cl + (size_t)b * 70 * 72 * 128;
    const float* ob = offb + (size_t)b * OFFP * HWSZ;

    // ---- precompute bilinear params (plane layout: conflict-free)
    for (int q = tid; q < TP * 16; q += 512) {
        int t = q >> 4, i = q & 15;
        float w00 = 0.f, w01 = 0.f, w10 = 0.f, w11 = 0.f;
        int o00 = 0, o01 = 0, o10 = 0, o11 = 0;
        if (t < T) {
            int p = px0 + i, h = p >> 6, w = p & 63;
            int ky = t / KK, kx = t % KK;
            float dy = ob[(size_t)(2 * t) * HWSZ + p];
            float dx = ob[(size_t)(2 * t + 1) * HWSZ + p];
            float py = (float)(h + ky - PAD) + dy;
            float pxs = (float)(w + kx - PAD) + dx;
            float y0f = floorf(py), x0f = floorf(pxs);
            float wy = py - y0f, wx = pxs - x0f;
            int y0 = (int)y0f, x0 = (int)x0f;
            int y1 = y0 + 1, x1 = x0 + 1;
            bool vy0 = (y0 >= 0) && (y0 < 64), vy1 = (y1 >= 0) && (y1 < 64);
            bool vx0 = (x0 >= 0) && (x0 < 64), vx1 = (x1 >= 0) && (x1 < 64);
            int cy0 = min(max(y0, 0), 63) + 3, cy1 = min(max(y1, 0), 63) + 3;
            int cx0 = min(max(x0, 0), 63) + 3, cx1 = min(max(x1, 0), 63) + 3;
            w00 = (vy0 && vx0) ? (1.f - wy) * (1.f - wx) : 0.f;
            w01 = (vy0 && vx1) ? (1.f - wy) * wx : 0.f;
            w10 = (vy1 && vx0) ? wy * (1.f - wx) : 0.f;
            w11 = (vy1 && vx1) ? wy * wx : 0.f;
            o00 = (cy0 * 72 + cx0) * 128;
            o01 = (cy0 * 72 + cx1) * 128;
            o10 = (cy1 * 72 + cx0) * 128;
            o11 = (cy1 * 72 + cx1) * 128;
        }
        pw4[0][q] = w00; pw4[1][q] = w01; pw4[2][q] = w10; pw4[3][q] = w11;
        po4[0][q] = o00; po4[1][q] = o01; po4[2][q] = o10; po4[3][q] = o11;
    }
    __syncthreads();

    int sub = tid & 15;          // 16B slice (8 channels)
    int i_s = (tid >> 4) & 15;   // sampling pixel
    int tp = tid >> 8;           // tap within pair (0/1)
    int wv = tid >> 6;           // MFMA wave -> M-tile
    int l = tid & 63;
    int col = l & 15, kg = l >> 4;
    f32x4 acc = (f32x4){0.f, 0.f, 0.f, 0.f};

    half8 rA[4], rB[4];
    float wgA[4], wgB[4];

    auto LOAD = [&](half8* r, float* wg, int pr) {
        if (pr >= S) return;
        int q = (pr * 2 + tp) * 16 + i_s;
        wg[0] = pw4[0][q]; wg[1] = pw4[1][q]; wg[2] = pw4[2][q]; wg[3] = pw4[3][q];
        r[0] = *(const half8*)(clb + po4[0][q] + sub * 8);
        r[1] = *(const half8*)(clb + po4[1][q] + sub * 8);
        r[2] = *(const half8*)(clb + po4[2][q] + sub * 8);
        r[3] = *(const half8*)(clb + po4[3][q] + sub * 8);
    };
    auto BW = [&](half8* r, float* wg, int pr) {
        if (pr >= S) return;
        half8 z;
#pragma unroll
        for (int j = 0; j < 8; ++j) {
            float v = wg[0] * (float)r[0][j] + wg[1] * (float)r[1][j] +
                      wg[2] * (float)r[2][j] + wg[3] * (float)r[3][j];
            z[j] = (_Float16)v;
        }
        *(half8*)&panel[pr & 1][tp][i_s][(sub ^ (i_s & 7)) * 8] = z;
    };
    auto MM = [&](int pr) {
        int buf = pr & 1;
        half8 af[8];
#pragma unroll
        for (int u = 0; u < 2; ++u) {
            int t = min(pr * 2 + u, T - 1);  // padded tap: weights arbitrary, B=0
            const _Float16* ap = wM + ((size_t)t * 128 + wv * 16 + col) * 128 + kg * 8;
#pragma unroll
            for (int cc = 0; cc < 4; ++cc) af[u * 4 + cc] = *(const half8*)(ap + cc * 32);
        }
#pragma unroll
        for (int u = 0; u < 2; ++u) {
#pragma unroll
            for (int cc = 0; cc < 4; ++cc) {
                half8 bf = *(const half8*)&panel[buf][u][col][((cc * 4 + kg) ^ (col & 7)) * 8];
                acc = __builtin_amdgcn_mfma_f32_16x16x32_f16(af[u * 4 + cc], bf, acc, 0, 0, 0);
            }
        }
    };

    LOAD(rA, wgA, 0);
    BW(rA, wgA, 0);
    LOAD(rB, wgB, 1);
    __syncthreads();  // panel for pair 0 ready
    for (int pr = 0; pr < S; pr += 2) {
        LOAD(rA, wgA, pr + 2);
        MM(pr);
        BW(rB, wgB, pr + 1);
        __syncthreads();
        if (pr + 1 < S) {
            LOAD(rB, wgB, pr + 3);
            MM(pr + 1);
            BW(rA, wgA, pr + 2);
            __syncthreads();
        }
    }

    int p = px0 + col, h = p >> 6, w = p & 63;
    half4 t4;
#pragma unroll
    for (int r = 0; r < 4; ++r) {
        int oc = wv * 16 + kg * 4 + r;
        t4[r] = (_Float16)gelu_f(acc[r] * (1.0f / 16.0f) + bias[oc]);
    }
    if (MODE == 0) {
        _Float16* dst = outH + (size_t)b * 70 * 72 * 128 +
                        ((size_t)(h + 3) * 72 + (3 + w)) * 128 + wv * 16 + kg * 4;
        *(half4*)dst = t4;
    } else {
        *(half4*)(outH + ((size_t)(b * HWSZ) + p) * 128 + wv * 16 + kg * 4) = t4;
    }
}

// ---------------- KZ: z = gelu(a) * g  (CL f16)
__global__ __launch_bounds__(256) void kz_cl(const _Float16* __restrict__ a5cl,
                                             const _Float16* __restrict__ gcl,
                                             _Float16* __restrict__ zbuf) {
    int idx = blockIdx.x * 256 + threadIdx.x;  // half8 index, 131072 total
    half8 a = ((const half8*)a5cl)[idx];
    half8 g = ((const half8*)gcl)[idx];
    half8 z;
#pragma unroll
    for (int j = 0; j < 8; ++j) z[j] = (_Float16)(gelu_f((float)a[j]) * (float)g[j]);
    ((half8*)zbuf)[idx] = z;
}

// ---------------- K6: out(B,HW,32) = z_cl(B,HW,128) @ w2(128,32) + b2
__global__ __launch_bounds__(256) void k6_cl(const _Float16* __restrict__ zbuf,
                                             const float* __restrict__ w2,
                                             const float* __restrict__ b2,
                                             float* __restrict__ out) {
    int idx = blockIdx.x * 256 + threadIdx.x;  // (b,p,d)
    int d = idx & 31;
    int p = (idx >> 5) & 4095;
    int b = idx >> 17;
    const _Float16* zr = zbuf + ((size_t)(b * HWSZ) + p) * 128;
    float acc = b2[d];
#pragma unroll
    for (int c8 = 0; c8 < 16; ++c8) {
        half8 v = *(const half8*)(zr + c8 * 8);
#pragma unroll
        for (int j = 0; j < 8; ++j) acc = fmaf((float)v[j], w2[(c8 * 8 + j) * 32 + d], acc);
    }
    out[idx] = acc;
}

extern "C" void kernel_launch(void* const* d_in, const int* in_sizes, int n_in,
                              void* d_out, int out_size, void* d_ws, size_t ws_size,
                              hipStream_t stream) {
    const float* x   = (const float*)d_in[0];
    const float* w1  = (const float*)d_in[1];
    const float* b1  = (const float*)d_in[2];
    const float* dww = (const float*)d_in[3];
    const float* dwb = (const float*)d_in[4];
    const float* pww = (const float*)d_in[5];
    const float* pwb = (const float*)d_in[6];
    const float* o3w = (const float*)d_in[7];
    const float* o3b = (const float*)d_in[8];
    const float* d3w = (const float*)d_in[9];
    const float* d3b = (const float*)d_in[10];
    const float* o4w = (const float*)d_in[11];
    const float* o4b = (const float*)d_in[12];
    const float* d4w = (const float*)d_in[13];
    const float* d4b = (const float*)d_in[14];
    const float* o5w = (const float*)d_in[15];
    const float* o5b = (const float*)d_in[16];
    const float* d5w = (const float*)d_in[17];
    const float* d5b = (const float*)d_in[18];
    const float* w2  = (const float*)d_in[19];
    const float* b2  = (const float*)d_in[20];

    float* ws = (float*)d_ws;
    float* offb = ws;                              // 1,048,576 f32
    _Float16* clA  = (_Float16*)(ws + 1048576);    // 1,290,240 f16
    _Float16* clB  = (_Float16*)(ws + 1693696);    // 1,290,240 f16
    _Float16* xicl = (_Float16*)(ws + 2338816);    // 1,048,576 f16
    _Float16* dcl  = (_Float16*)(ws + 2863104);    // 1,048,576 f16
    _Float16* gcl  = (_Float16*)(ws + 3387392);    // 1,048,576 f16
    _Float16* a5cl = (_Float16*)(ws + 3911680);    // 1,048,576 f16
    _Float16* zbuf = (_Float16*)(ws + 4435968);    // 1,048,576 f16
    _Float16* wA3  = (_Float16*)(ws + 4960256);    // 49*128*128 f16
    _Float16* wA4  = (_Float16*)(ws + 5361664);    // 9*32*128
    _Float16* wA5  = (_Float16*)(ws + 5380096);    // 25*64*128
    _Float16* wM3  = (_Float16*)(ws + 5482496);    // 49*128*128
    _Float16* wM4  = (_Float16*)(ws + 5883904);    // 9*128*128
    _Float16* wM5  = (_Float16*)(ws + 5957632);    // 25*128*128
    _Float16* dwt  = (_Float16*)(ws + 6162432);    // 9*128
    _Float16* pwt  = (_Float16*)(ws + 6163008);    // 256*128

    // weight transforms
    dwtk<<<5, 256, 0, stream>>>(dww, dwt);
    pcast<<<128, 256, 0, stream>>>(pww, pwt);
    wtr<<<3136, 256, 0, stream>>>(o3w, wA3, 49, 128, 98, 256.f);
    wtr<<<144,  256, 0, stream>>>(o4w, wA4, 9,  32,  18, 256.f);
    wtr<<<800,  256, 0, stream>>>(o5w, wA5, 25, 64,  50, 256.f);
    wtr<<<3136, 256, 0, stream>>>(d3w, wM3, 49, 128, 128, 16.f);
    wtr<<<576,  256, 0, stream>>>(d4w, wM4, 9,  128, 128, 16.f);
    wtr<<<1600, 256, 0, stream>>>(d5w, wM5, 25, 128, 128, 16.f);
    zcl<<<2520, 256, 0, stream>>>((unsigned int*)clA);
    zcl<<<2520, 256, 0, stream>>>((unsigned int*)clB);

    // front of net
    k1_cl<<<4096, 256, 0, stream>>>(x, w1, b1, xicl);
    k2_cl<<<512, 256, 0, stream>>>(xicl, dwt, dwb, dcl);
    k3G<<<dim3(512, 2), 512, 0, stream>>>(dcl, pwt, pwb, clA, gcl);

    // d3: k=7, pad=3, T=49; off M padded 98->128 (MT=8, NA=2, WPX=32)
    k4Gv3<7, 3, 49, 8, 1, 2, 32><<<256, 512, 0, stream>>>(clA, wA3, o3b, offb, 98);
    k5Gv3<7, 3, 49, 0><<<512, 512, 0, stream>>>(clA, offb, 128, wM3, d3b, clB);

    // d4: k=3, pad=1, T=9; OCp=32 (MT=2, NG=4, NA=1, WPX=64)
    k4Gv3<3, 1, 9, 2, 4, 1, 64><<<128, 512, 0, stream>>>(clB, wA4, o4b, offb, 18);
    k5Gv3<3, 1, 9, 0><<<512, 512, 0, stream>>>(clB, offb, 32, wM4, d4b, clA);

    // d5: k=5, pad=2, T=25; OCp=64 (MT=4, NG=2, NA=1, WPX=32) -> flat CL f16
    k4Gv3<5, 2, 25, 4, 2, 1, 32><<<256, 512, 0, stream>>>(clA, wA5, o5b, offb, 50);
    k5Gv3<5, 2, 25, 2><<<512, 512, 0, stream>>>(clA, offb, 64, wM5, d5b, a5cl);

    // tail
    kz_cl<<<512, 256, 0, stream>>>(a5cl, gcl, zbuf);
    k6_cl<<<1024, 256, 0, stream>>>(zbuf, w2, b2, (float*)d_out);
}